// Round 6
// baseline (473.120 us; speedup 1.0000x reference)
//
#include <hip/hip_runtime.h>
#include <stdint.h>
#include <math.h>

// B=4, T=2048, D=2048, HEADS=16.  Inputs/outputs fp32; internal bf16 MFMA.
//
// Pipeline: cast -> A: kv^T -> T: transpose -> B: scores -> S: softmax ->
//           C: q = a@vT^T -> D: perm(q)@w_dense^T + bias.
//
// GEMM core: 256x256 tile, 2 K-tiles/iter, TWO phases per K-tile (one per
// kh-half), ONE barrier per phase -> 2 barriers/K-tile (was 4 in round 5,
// 8 in round 4).  Each phase: RD12 (A mi0-7 + B ni0-3, 12x ds_read_b128) +
// 4x global_load_lds staging + vmcnt(8), BARRIER, then a single 32-MFMA
// prioritized cluster.  Next phase's RD12/STG interleave into the cluster.
//
// ROUND-6 CHANGE (single change): merge the mi0-3/mi4-7 sub-phases.  NOTE:
// the cheaper-looking "RD8 pre-barrier + RD4 post-barrier" split is RACY in
// one-barrier form: wave X's STG into buf.kh0 (phase beta segment) and wave
// Y's RD4 of buf.kh0 (same segment) are unordered.  RD12 puts every reader
// of a region strictly before the barrier that precedes the region's next
// staging -> anti-dep holds with a full barrier between.
//
// Ledger (identical staging slots/offsets to round 5; tiles t0=2it buf0,
// t1=2it+1 buf1; 4 loads per phase):
//  t0a: RD12(kh0,b0) STG A+B(t1.kh1->b1)@96  VM(8) BAR MFMA32
//  t0b: RD12(kh1,b0) STG A+B(t2.kh0->b0)@128 VM(8) BAR MFMA32
//  t1a: RD12(kh0,b1) STG A+B(t2.kh1->b0)@160 VM(8) BAR MFMA32
//  t1b: RD12(kh1,b1) STG A+B(t3.kh0->b1)@192 VM(8) BAR MFMA32
//  data-ready: region staged 3 phases before its read-phase; VM(8) two
//   phases later retires it (newest 8 = the two younger phases' loads), and
//   the following BAR precedes the read segment.  e.g. t0.kh0 staged at
//   p0b(@prev+128), retired by VM(8)@p1b, read after BAR(p1b).  Checked for
//   kh0/kh1 of both parities.
//  anti-dep: a region's readers all sit before BAR(p); its next staging is
//   issued in the segment after BAR(p).  e.g. STG@128 (buf0.kh0) issued in
//   t0b segment (after BAR(t0a)); last readers = t0a.RD12 (before BAR(t0a)).
//  tail (last 2 tiles): only A/B@96 staged; waits 8 -> 4 -> 4 -> 0.
//  prologue: t0.kh0 t0.kh1 t1.kh0 (12 loads), VM(8) -> t0.kh0 landed, BAR.
//  MFMA accumulate order per acc[m][n] unchanged (kh0 then kh1 per tile)
//  -> bit-exact vs round 5.
//
//  - 512 thr = 8 waves (2M x 4N), per-wave output 128x64 (acc[8][4] f32x4).
//  - LDS = 2dbuf x {A,B} x [2kh][256r x 32c] bf16 = 128 KiB dynamic.
//  - Staging: global_load_lds width=16, LINEAR LDS dest; global source chunk
//    g = (tid&3)^((tid>>3)&3) (involution with read-side XOR) -> 0 bank
//    conflicts (verified).
//  - Register note: 12 live bf16x8 frags (+16 VGPR vs round 5's 8) + 128
//    acc; est ~252/256 at 2 waves/SIMD.  VGPR_Count is the spill canary.
//  - Grids: gridDim.x % 8 == 0, bn fastest => B-panels XCD-affine; no swizzle.

typedef __bf16 bf16x8 __attribute__((ext_vector_type(8)));
typedef float  f32x4  __attribute__((ext_vector_type(4)));

typedef __attribute__((address_space(3))) uint32_t lds_u32_t;
typedef __attribute__((address_space(1))) const uint32_t glb_u32_t;

__device__ __forceinline__ float bf2f(uint16_t u) {
  union { uint32_t i; float f; } c; c.i = ((uint32_t)u) << 16; return c.f;
}
__device__ __forceinline__ uint16_t f2bf(float f) {
  union { float f; uint32_t i; } c; c.f = f;
  uint32_t i = c.i;
  return (uint16_t)((i + 0x7fffu + ((i >> 16) & 1u)) >> 16);  // RNE
}

__device__ __forceinline__ void glds16(const uint16_t* g, const char* l) {
  __builtin_amdgcn_global_load_lds((glb_u32_t*)g, (lds_u32_t*)l, 16, 0, 0);
}

#define SCHED0() __builtin_amdgcn_sched_barrier(0)
#define BARRIER() do { SCHED0(); __builtin_amdgcn_s_barrier(); SCHED0(); } while (0)
#define VMCNT(n_) asm volatile("s_waitcnt vmcnt(" #n_ ")")

// ---- fused fp32 -> bf16 cast over x|w_qk|w_dense -----------------------------
#define NX4 4194304u
#define NW4 2097152u
#define ND4 1048576u
__global__ __launch_bounds__(256) void k_cast_all(
    const float* __restrict__ x, const float* __restrict__ wqk,
    const float* __restrict__ wd, uint16_t* __restrict__ dst) {
  uint32_t i = blockIdx.x * 256 + threadIdx.x;
  float4 v;
  if (i < NX4)            v = reinterpret_cast<const float4*>(x)[i];
  else if (i < NX4 + NW4) v = reinterpret_cast<const float4*>(wqk)[i - NX4];
  else                    v = reinterpret_cast<const float4*>(wd)[i - NX4 - NW4];
  ushort4 o;
  o.x = f2bf(v.x); o.y = f2bf(v.y); o.z = f2bf(v.z); o.w = f2bf(v.w);
  reinterpret_cast<ushort4*>(dst)[i] = o;
}

// ---- 256x256 GEMM core, 2 phases/K-tile, 2 K-tiles per iteration ------------
// aR0/aR1/bR0/bR1: per-thread staging sources, rows (tid>>2) and (tid>>2)+128
// of the 256-row tile, at k=0, swizzled chunk offset already added.
__device__ __forceinline__ void gemm256_core(
    const uint16_t* aR0, const uint16_t* aR1,
    const uint16_t* bR0, const uint16_t* bR1,
    int K, f32x4 acc[8][4])
{
  extern __shared__ uint4 smem_u4[];
  char* smem = (char*)smem_u4;
  const int tid = threadIdx.x;
  const int w = tid >> 6, l = tid & 63;
  const int wm = (w >> 2) * 128, wn = (w & 3) * 64;
  const int frow = l & 15, fkc = l >> 4;
  // read-side chunk swizzle: chunk' = fkc ^ ((frow>>1)&3)  (fixed per lane)
  const uint32_t chunk = (uint32_t)((fkc ^ ((frow >> 1) & 3)) * 16);
  const uint32_t aBase = (uint32_t)(wm + frow) * 64 + chunk;           // +mi*1024 +kh*16384 +buf*32768
  const uint32_t bBase = 65536u + (uint32_t)(wn + frow) * 64 + chunk;  // +ni*1024 +kh*16384 +buf*32768
  char* lW = smem + (uint32_t)w * 1024u;   // per-wave staging dest base
  const int NIT = K >> 7;                  // iterations of 2 K-tiles; K % 128 == 0

#define LDSA(kh_, buf_, half_) (lW + ((buf_) * 32768u + (kh_) * 16384u + (half_) * 8192u))
#define LDSB(kh_, buf_, half_) (lW + (65536u + (buf_) * 32768u + (kh_) * 16384u + (half_) * 8192u))
// off_ is the FULL K-offset in elements (tile*64 + kh*32); kh_ selects the LDS
// destination region only.
#define STG_A(off_, kh_, buf_) do { \
    glds16(aR0 + (off_), LDSA(kh_, buf_, 0)); \
    glds16(aR1 + (off_), LDSA(kh_, buf_, 1)); } while (0)
#define STG_B(off_, kh_, buf_) do { \
    glds16(bR0 + (off_), LDSB(kh_, buf_, 0)); \
    glds16(bR1 + (off_), LDSB(kh_, buf_, 1)); } while (0)
#define RD_A(mi_, kh_, buf_) \
    (*reinterpret_cast<const bf16x8*>(smem + (aBase + (mi_) * 1024u + (kh_) * 16384u + (buf_) * 32768u)))
#define RD_B(ni_, kh_, buf_) \
    (*reinterpret_cast<const bf16x8*>(smem + (bBase + (ni_) * 1024u + (kh_) * 16384u + (buf_) * 32768u)))
// read all 12 fragments of one kh-half (A mi0-7, B ni0-3)
#define PH_RD12(kh_, buf_) do { \
    a0 = RD_A(0, kh_, buf_); a1 = RD_A(1, kh_, buf_); \
    a2 = RD_A(2, kh_, buf_); a3 = RD_A(3, kh_, buf_); \
    a4 = RD_A(4, kh_, buf_); a5 = RD_A(5, kh_, buf_); \
    a6 = RD_A(6, kh_, buf_); a7 = RD_A(7, kh_, buf_); \
    b0 = RD_B(0, kh_, buf_); b1 = RD_B(1, kh_, buf_); \
    b2 = RD_B(2, kh_, buf_); b3 = RD_B(3, kh_, buf_); } while (0)
#define MFMA8(ai_, mi_) do { \
    acc[mi_][0] = __builtin_amdgcn_mfma_f32_16x16x32_bf16(ai_, b0, acc[mi_][0], 0, 0, 0); \
    acc[mi_][1] = __builtin_amdgcn_mfma_f32_16x16x32_bf16(ai_, b1, acc[mi_][1], 0, 0, 0); \
    acc[mi_][2] = __builtin_amdgcn_mfma_f32_16x16x32_bf16(ai_, b2, acc[mi_][2], 0, 0, 0); \
    acc[mi_][3] = __builtin_amdgcn_mfma_f32_16x16x32_bf16(ai_, b3, acc[mi_][3], 0, 0, 0); \
  } while (0)
// one barrier per phase, then the full 32-MFMA prioritized cluster
#define MFMA_PH() do { \
    BARRIER(); \
    __builtin_amdgcn_s_setprio(1); \
    MFMA8(a0, 0); MFMA8(a1, 1); MFMA8(a2, 2); MFMA8(a3, 3); \
    MFMA8(a4, 4); MFMA8(a5, 5); MFMA8(a6, 6); MFMA8(a7, 7); \
    __builtin_amdgcn_s_setprio(0); } while (0)

  // ---- prologue: tile0 kh0@0 kh1@32 + tile1 kh0@64 --------------------------
  STG_A(0, 0, 0); STG_B(0, 0, 0); STG_A(32, 1, 0); STG_B(32, 1, 0);
  STG_A(64, 0, 1); STG_B(64, 0, 1);
  VMCNT(8);   // newest 8 = t0.kh1 + t1.kh0 -> t0.kh0 landed

  bf16x8 a0, a1, a2, a3, a4, a5, a6, a7, b0, b1, b2, b3;
  BARRIER();   // BAR0: t0.kh0 published to all waves

  // ---- steady state: branch-free, 2 K-tiles / iteration ----------------------
  for (int it = 0; it < NIT - 1; ++it) {
    // ===== tile t0 (buf 0) =====
    PH_RD12(0, 0); STG_A(96, 1, 1);  STG_B(96, 1, 1);  VMCNT(8); MFMA_PH();  // t0a
    PH_RD12(1, 0); STG_A(128, 0, 0); STG_B(128, 0, 0); VMCNT(8); MFMA_PH();  // t0b
    // ===== tile t1 (buf 1) =====
    PH_RD12(0, 1); STG_A(160, 1, 0); STG_B(160, 1, 0); VMCNT(8); MFMA_PH();  // t1a
    PH_RD12(1, 1); STG_A(192, 0, 1); STG_B(192, 0, 1); VMCNT(8); MFMA_PH();  // t1b
    aR0 += 128; aR1 += 128; bR0 += 128; bR1 += 128;
  }

  // ---- tail: last 2 tiles (t0 buf0 / t1 buf1); only A/B(t1,kh1)@96 to stage --
  PH_RD12(0, 0); STG_A(96, 1, 1); STG_B(96, 1, 1); VMCNT(8); MFMA_PH();
  PH_RD12(1, 0); VMCNT(4); MFMA_PH();   // newest 4 = @96 stg -> t0.kh1 landed
  PH_RD12(0, 1); VMCNT(4); MFMA_PH();   // t1.kh0 (prev iter) landed
  PH_RD12(1, 1); VMCNT(0); MFMA_PH();   // t1.kh1 (@96) landed
#undef LDSA
#undef LDSB
#undef STG_A
#undef STG_B
#undef RD_A
#undef RD_B
#undef PH_RD12
#undef MFMA8
#undef MFMA_PH
}

// staging source-column swizzle (involution with read side): g = (tid&3)^((tid>>3)&3)
__device__ __forceinline__ int stage_co() {
  const int tid = threadIdx.x;
  return (((tid & 3) ^ ((tid >> 3) & 3)) * 8);
}

// ---- stage A: kv^T, block-uniform split-store into k0T / vT ------------------
__global__ __launch_bounds__(512, 2) void k_gemm_kv(
    const uint16_t* __restrict__ W,    // wqkb 4096x2048
    const uint16_t* __restrict__ X,    // xb   8192x2048
    uint16_t* __restrict__ k0T,        // 2048x8192
    uint16_t* __restrict__ vT)         // 2048x8192
{
  const int tid = threadIdx.x;
  const int bm = blockIdx.y, bn = blockIdx.x;
  const int r0 = tid >> 2, co = stage_co();
  const uint16_t* aR0 = W + (size_t)(bm * 256 + r0) * 2048 + co;
  const uint16_t* aR1 = W + (size_t)(bm * 256 + 128 + r0) * 2048 + co;
  const uint16_t* bR0 = X + (size_t)(bn * 256 + r0) * 2048 + co;
  const uint16_t* bR1 = X + (size_t)(bn * 256 + 128 + r0) * 2048 + co;
  f32x4 acc[8][4];
#pragma unroll
  for (int i = 0; i < 8; ++i)
#pragma unroll
    for (int j = 0; j < 4; ++j) acc[i][j] = (f32x4){0.f, 0.f, 0.f, 0.f};
  gemm256_core(aR0, aR1, bR0, bR1, 2048, acc);
  const int w = tid >> 6, l = tid & 63;
  const int wm = (w >> 2) * 128, wn = (w & 3) * 64;
  const int cr = (l >> 4) * 4, cc = l & 15;
  uint16_t* Cb = (bm < 8) ? k0T : vT;
  const int rb = (bm & 7) * 256;
#pragma unroll
  for (int mi = 0; mi < 8; ++mi)
#pragma unroll
    for (int ni = 0; ni < 4; ++ni)
#pragma unroll
      for (int g = 0; g < 4; ++g) {
        int lr = rb + wm + mi * 16 + cr + g;
        int bt = bn * 256 + wn + ni * 16 + cc;
        Cb[(size_t)lr * 8192 + bt] = f2bf(acc[mi][ni][g]);
      }
}

// ---- generic batched A@B^T (both K-contig), scaled bf16 store ----------------
__global__ __launch_bounds__(512, 2) void k_gemm_bt(
    const uint16_t* __restrict__ A, int lda, long sA,
    const uint16_t* __restrict__ B, int ldb, long sB,
    uint16_t* __restrict__ C, int ldc, long sC,
    int K, float scale)
{
  const int z = blockIdx.z;
  A += (size_t)z * sA; B += (size_t)z * sB; C += (size_t)z * sC;
  const int tid = threadIdx.x;
  const int bm = blockIdx.y, bn = blockIdx.x;
  const int r0 = tid >> 2, co = stage_co();
  const uint16_t* aR0 = A + (size_t)(bm * 256 + r0) * lda + co;
  const uint16_t* aR1 = A + (size_t)(bm * 256 + 128 + r0) * lda + co;
  const uint16_t* bR0 = B + (size_t)(bn * 256 + r0) * ldb + co;
  const uint16_t* bR1 = B + (size_t)(bn * 256 + 128 + r0) * ldb + co;
  f32x4 acc[8][4];
#pragma unroll
  for (int i = 0; i < 8; ++i)
#pragma unroll
    for (int j = 0; j < 4; ++j) acc[i][j] = (f32x4){0.f, 0.f, 0.f, 0.f};
  gemm256_core(aR0, aR1, bR0, bR1, K, acc);
  const int w = tid >> 6, l = tid & 63;
  const int wm = (w >> 2) * 128, wn = (w & 3) * 64;
  const int cr = (l >> 4) * 4, cc = l & 15;
#pragma unroll
  for (int mi = 0; mi < 8; ++mi)
#pragma unroll
    for (int ni = 0; ni < 4; ++ni)
#pragma unroll
      for (int g = 0; g < 4; ++g) {
        int grow = bm * 256 + wm + mi * 16 + cr + g;
        int gcol = bn * 256 + wn + ni * 16 + cc;
        C[(size_t)grow * ldc + gcol] = f2bf(acc[mi][ni][g] * scale);
      }
}

// ---- stage D: permuted-A GEMM + fp32 bias/store into d_out -------------------
__device__ __forceinline__ size_t qrow_off(int rr) {
  // rr = b'*2048 + t' ; q row = (b_i, i), b_i=(t'>>4)&3, i=(t'&15)*128+b'*32+(t'>>6)
  int bp = rr >> 11, tp = rr & 2047;
  int bi = (tp >> 4) & 3;
  int i  = (tp & 15) * 128 + bp * 32 + (tp >> 6);
  return ((size_t)bi * 2048 + (size_t)i) * 2048;
}

__global__ __launch_bounds__(512, 2) void k_gemm_out(
    const uint16_t* __restrict__ Q,     // qb (4,2048,2048) bf16
    const uint16_t* __restrict__ W,     // wdb 2048x2048 bf16
    const float*    __restrict__ bias,  // b_dense fp32 (2048)
    float*          __restrict__ Out)   // d_out 8192x2048 fp32
{
  const int tid = threadIdx.x;
  const int bm = blockIdx.y, bn = blockIdx.x;
  const int r0 = tid >> 2, co = stage_co();
  const uint16_t* aR0 = Q + qrow_off(bm * 256 + r0) + co;
  const uint16_t* aR1 = Q + qrow_off(bm * 256 + 128 + r0) + co;
  const uint16_t* bR0 = W + (size_t)(bn * 256 + r0) * 2048 + co;
  const uint16_t* bR1 = W + (size_t)(bn * 256 + 128 + r0) * 2048 + co;
  f32x4 acc[8][4];
#pragma unroll
  for (int i = 0; i < 8; ++i)
#pragma unroll
    for (int j = 0; j < 4; ++j) acc[i][j] = (f32x4){0.f, 0.f, 0.f, 0.f};
  gemm256_core(aR0, aR1, bR0, bR1, 2048, acc);
  const int w = tid >> 6, l = tid & 63;
  const int wm = (w >> 2) * 128, wn = (w & 3) * 64;
  const int cr = (l >> 4) * 4, cc = l & 15;
#pragma unroll
  for (int mi = 0; mi < 8; ++mi)
#pragma unroll
    for (int ni = 0; ni < 4; ++ni)
#pragma unroll
      for (int g = 0; g < 4; ++g) {
        int grow = bm * 256 + wm + mi * 16 + cr + g;
        int gcol = bn * 256 + wn + ni * 16 + cc;
        Out[(size_t)grow * 2048 + gcol] = acc[mi][ni][g] + bias[gcol];
      }
}

// ---- transpose vT (2048x8192) -> Vn (8192x2048) ------------------------------
__global__ __launch_bounds__(256) void k_transpose(
    const uint16_t* __restrict__ src, uint16_t* __restrict__ dst)
{
  __shared__ uint16_t tile[64][65];
  const int tid = threadIdx.x;
  const int bx = blockIdx.x;
  const int by = blockIdx.y;
  const int cu = tid & 31, r0 = tid >> 5;
#pragma unroll
  for (int p = 0; p < 8; ++p) {
    int r = p * 8 + r0;
    uint32_t v = *reinterpret_cast<const uint32_t*>(
        &src[(size_t)(by * 64 + r) * 8192 + bx * 64 + cu * 2]);
    tile[r][cu * 2]     = (uint16_t)(v & 0xffffu);
    tile[r][cu * 2 + 1] = (uint16_t)(v >> 16);
  }
  __syncthreads();
#pragma unroll
  for (int p = 0; p < 8; ++p) {
    int r = p * 8 + r0;
    uint32_t lo = tile[cu * 2][r], hi = tile[cu * 2 + 1][r];
    *reinterpret_cast<uint32_t*>(
        &dst[(size_t)(bx * 64 + r) * 2048 + by * 64 + cu * 2]) = lo | (hi << 16);
  }
}

// ---- row softmax (bf16 in place), 1 block per row of 2048 --------------------
__global__ __launch_bounds__(256) void k_softmax(uint16_t* __restrict__ s)
{
  uint16_t* p = s + (size_t)blockIdx.x * 2048;
  const int tid = threadIdx.x;
  uint4 raw = reinterpret_cast<const uint4*>(p)[tid];
  uint32_t u[4] = {raw.x, raw.y, raw.z, raw.w};
  float x[8];
#pragma unroll
  for (int i = 0; i < 4; ++i) {
    x[2 * i]     = bf2f((uint16_t)(u[i] & 0xffffu));
    x[2 * i + 1] = bf2f((uint16_t)(u[i] >> 16));
  }
  float m = x[0];
#pragma unroll
  for (int i = 1; i < 8; ++i) m = fmaxf(m, x[i]);
#pragma unroll
  for (int o = 32; o; o >>= 1) m = fmaxf(m, __shfl_xor(m, o, 64));
  __shared__ float redm[4], reds[4];
  if ((tid & 63) == 0) redm[tid >> 6] = m;
  __syncthreads();
  m = fmaxf(fmaxf(redm[0], redm[1]), fmaxf(redm[2], redm[3]));
  float sum = 0.f;
#pragma unroll
  for (int i = 0; i < 8; ++i) { x[i] = __expf(x[i] - m); sum += x[i]; }
#pragma unroll
  for (int o = 32; o; o >>= 1) sum += __shfl_xor(sum, o, 64);
  if ((tid & 63) == 0) reds[tid >> 6] = sum;
  __syncthreads();
  sum = reds[0] + reds[1] + reds[2] + reds[3];
  float inv = 1.0f / sum;
  uint32_t ou[4];
#pragma unroll
  for (int i = 0; i < 4; ++i) {
    uint32_t lo = f2bf(x[2 * i] * inv);
    uint32_t hi = f2bf(x[2 * i + 1] * inv);
    ou[i] = lo | (hi << 16);
  }
  reinterpret_cast<uint4*>(p)[tid] = make_uint4(ou[0], ou[1], ou[2], ou[3]);
}

// ------------------------------------------------------------------------------
extern "C" void kernel_launch(void* const* d_in, const int* in_sizes, int n_in,
                              void* d_out, int out_size, void* d_ws, size_t ws_size,
                              hipStream_t stream) {
  const float* x       = (const float*)d_in[0];
  const float* w_qk    = (const float*)d_in[1];
  const float* w_dense = (const float*)d_in[2];
  const float* b_dense = (const float*)d_in[3];
  float* out = (float*)d_out;

  static int attr_done = 0;
  if (!attr_done) {
    (void)hipFuncSetAttribute(reinterpret_cast<const void*>(k_gemm_kv),
                              hipFuncAttributeMaxDynamicSharedMemorySize, 131072);
    (void)hipFuncSetAttribute(reinterpret_cast<const void*>(k_gemm_bt),
                              hipFuncAttributeMaxDynamicSharedMemorySize, 131072);
    (void)hipFuncSetAttribute(reinterpret_cast<const void*>(k_gemm_out),
                              hipFuncAttributeMaxDynamicSharedMemorySize, 131072);
    attr_done = 1;
  }

  const size_t NX = 4ull * 2048 * 2048;
  const size_t NW = 4096ull * 2048;
  const size_t ND = 2048ull * 2048;

  // d_ws layout (bf16): xb | wqkb | wdb | k0T | vT   (126 MB peak)
  uint16_t* xb   = (uint16_t*)d_ws;
  uint16_t* wqkb = xb + NX;
  uint16_t* wdb  = wqkb + NW;
  uint16_t* k0T  = wdb + ND;
  uint16_t* vT   = k0T + NX;
  uint16_t* qb   = xb;                    // alias: xb dead after stage A
  uint16_t* Vn   = (uint16_t*)d_out;      // d_out as scratch (dead before D)
  uint16_t* sb   = Vn + NX;

  const float scale = (float)(1.0 / sqrt(0.5 * 2048.0 * 2047.0));

  k_cast_all<<<dim3((NX4 + NW4 + ND4) / 256), 256, 0, stream>>>(x, w_qk, w_dense, xb);

  // A: kv^T  (M=4096 e, N=8192 bt, K=2048)
  k_gemm_kv<<<dim3(32, 16), 512, 131072, stream>>>(wqkb, xb, k0T, vT);
  // T: vT -> Vn
  k_transpose<<<dim3(128, 32), 256, 0, stream>>>(vT, Vn);
  // B: s = scale * k0T @ Vn^T
  k_gemm_bt<<<dim3(8, 8, 4), 512, 131072, stream>>>(
      k0T, 8192, 2048L, Vn, 2048, 2048L * 2048L, sb, 2048, 2048L * 2048L, 2048, scale);
  // S: softmax rows
  k_softmax<<<dim3(8192), 256, 0, stream>>>(sb);
  // C: q = a @ vT^T
  k_gemm_bt<<<dim3(8, 8, 4), 512, 131072, stream>>>(
      sb, 2048, 2048L * 2048L, vT, 8192, 2048L, qb, 2048, 2048L * 2048L, 2048, 1.0f);
  // D: out = perm(q) @ w_dense^T + bias -> fp32
  k_gemm_out<<<dim3(8, 32), 512, 131072, stream>>>(qb, wdb, b_dense, out);
}